// Round 1
// baseline (890.248 us; speedup 1.0000x reference)
//
#include <hip/hip_runtime.h>

// ---------------- constants ----------------
#define B_ 4
#define Hh_ 32
#define Ww_ 32
#define L_ 1024
#define HID_ 512
#define DI_ 1024
#define N_ 64
#define R_ 32
#define K_ 4
#define MLP_ 2048

typedef __bf16 bf16x8 __attribute__((ext_vector_type(8)));
typedef float f32x4 __attribute__((ext_vector_type(4)));

__device__ __forceinline__ unsigned short f2bf(float f) {
  unsigned int u = __builtin_bit_cast(unsigned int, f);
  return (unsigned short)((u + 0x7FFFu + ((u >> 16) & 1u)) >> 16);
}

// ---------------- transpose + cast weights: src (K,N) f32 -> dst (N,K) bf16 ----------------
__global__ __launch_bounds__(256) void transpose_cast(
    const float* __restrict__ src, unsigned short* __restrict__ dst, int K, int N) {
  __shared__ float t[32][33];
  int nb = blockIdx.x * 32, kb = blockIdx.y * 32;
  int tx = threadIdx.x & 31, ty = threadIdx.x >> 5;
  for (int r = ty; r < 32; r += 8) t[r][tx] = src[(size_t)(kb + r) * N + nb + tx];
  __syncthreads();
  for (int r = ty; r < 32; r += 8) dst[(size_t)(nb + r) * K + kb + tx] = f2bf(t[tx][r]);
}

// ---------------- LayerNorm over 512, wave per row ----------------
__global__ __launch_bounds__(256) void ln_kernel(
    const float* __restrict__ in, float* __restrict__ out,
    const float* __restrict__ w, const float* __restrict__ bb) {
  int row = blockIdx.x * 4 + (threadIdx.x >> 6);
  int lane = threadIdx.x & 63;
  const float* p = in + (size_t)row * HID_;
  float4 v0 = *(const float4*)(p + lane * 4);
  float4 v1 = *(const float4*)(p + 256 + lane * 4);
  float s = v0.x + v0.y + v0.z + v0.w + v1.x + v1.y + v1.z + v1.w;
  float q = v0.x * v0.x + v0.y * v0.y + v0.z * v0.z + v0.w * v0.w +
            v1.x * v1.x + v1.y * v1.y + v1.z * v1.z + v1.w * v1.w;
  #pragma unroll
  for (int m = 1; m < 64; m <<= 1) { s += __shfl_xor(s, m, 64); q += __shfl_xor(q, m, 64); }
  float mean = s * (1.f / 512.f);
  float var = q * (1.f / 512.f) - mean * mean;
  float rstd = rsqrtf(var + 1e-5f);
  float4 w0 = *(const float4*)(w + lane * 4);
  float4 w1 = *(const float4*)(w + 256 + lane * 4);
  float4 b0 = *(const float4*)(bb + lane * 4);
  float4 b1 = *(const float4*)(bb + 256 + lane * 4);
  float* o = out + (size_t)row * HID_;
  float4 r0, r1;
  r0.x = (v0.x - mean) * rstd * w0.x + b0.x;
  r0.y = (v0.y - mean) * rstd * w0.y + b0.y;
  r0.z = (v0.z - mean) * rstd * w0.z + b0.z;
  r0.w = (v0.w - mean) * rstd * w0.w + b0.w;
  r1.x = (v1.x - mean) * rstd * w1.x + b1.x;
  r1.y = (v1.y - mean) * rstd * w1.y + b1.y;
  r1.z = (v1.z - mean) * rstd * w1.z + b1.z;
  r1.w = (v1.w - mean) * rstd * w1.w + b1.w;
  *(float4*)(o + lane * 4) = r0;
  *(float4*)(o + 256 + lane * 4) = r1;
}

// ---------------- MFMA GEMM: A (M,K) f32, BT (N,K) bf16, C (M,N) f32 ----------------
// EPI: 0 = plain, 1 = +resid, 2 = +bias then exact gelu, 3 = +bias +resid
#define BM 128
#define BN 128
#define BK 32
#define LST 40  // LDS row stride in bf16 units (80B, 16B-aligned, conflict-light)

template <int EPI>
__global__ __launch_bounds__(256) void gemm_kernel(
    const float* __restrict__ A, const unsigned short* __restrict__ BT,
    float* __restrict__ C, int M, int N, int K,
    const float* __restrict__ bias, const float* __restrict__ resid) {
  __shared__ __align__(16) unsigned short As[BM * LST];
  __shared__ __align__(16) unsigned short Bs[BN * LST];
  int tid = threadIdx.x;
  int lane = tid & 63, wv = tid >> 6;
  int wm = wv >> 1, wn = wv & 1;
  int m0 = blockIdx.y * BM, n0 = blockIdx.x * BN;
  f32x4 acc[4][4] = {};
  int sr = tid >> 3, sc = (tid & 7) * 4;
  int kk = (lane >> 4) * 8;
  int rA = wm * 64 + (lane & 15);
  int rB = wn * 64 + (lane & 15);
  for (int k0 = 0; k0 < K; k0 += BK) {
    __syncthreads();
    #pragma unroll
    for (int p = 0; p < 4; ++p) {
      int r = sr + p * 32;
      float4 av = *(const float4*)(A + (size_t)(m0 + r) * K + k0 + sc);
      unsigned int lo = (unsigned int)f2bf(av.x) | ((unsigned int)f2bf(av.y) << 16);
      unsigned int hi = (unsigned int)f2bf(av.z) | ((unsigned int)f2bf(av.w) << 16);
      *(uint2*)&As[r * LST + sc] = make_uint2(lo, hi);
      uint2 bv = *(const uint2*)(BT + (size_t)(n0 + r) * K + k0 + sc);
      *(uint2*)&Bs[r * LST + sc] = bv;
    }
    __syncthreads();
    bf16x8 fa[4], fb[4];
    #pragma unroll
    for (int i = 0; i < 4; ++i) {
      fa[i] = *(const bf16x8*)&As[(rA + i * 16) * LST + kk];
      fb[i] = *(const bf16x8*)&Bs[(rB + i * 16) * LST + kk];
    }
    #pragma unroll
    for (int i = 0; i < 4; ++i)
      #pragma unroll
      for (int j = 0; j < 4; ++j)
        acc[i][j] = __builtin_amdgcn_mfma_f32_16x16x32_bf16(fa[i], fb[j], acc[i][j], 0, 0, 0);
  }
  int crow0 = m0 + wm * 64 + (lane >> 4) * 4, ccol0 = n0 + wn * 64 + (lane & 15);
  #pragma unroll
  for (int i = 0; i < 4; ++i) {
    #pragma unroll
    for (int j = 0; j < 4; ++j) {
      int col = ccol0 + j * 16;
      #pragma unroll
      for (int r = 0; r < 4; ++r) {
        int row = crow0 + i * 16 + r;
        float v = acc[i][j][r];
        if (EPI == 1) v += resid[(size_t)row * N + col];
        if (EPI == 2) { v += bias[col]; v = 0.5f * v * (1.f + erff(v * 0.70710678f)); }
        if (EPI == 3) v += bias[col] + resid[(size_t)row * N + col];
        C[(size_t)row * N + col] = v;
      }
    }
  }
}

// ---------------- depthwise 3x3 conv + bias + SiLU (channels-last) ----------------
__global__ __launch_bounds__(256) void conv_kernel(
    const float* __restrict__ xz, const float* __restrict__ cw,
    const float* __restrict__ cb, float* __restrict__ xa) {
  int idx = blockIdx.x * 256 + threadIdx.x;  // (b,l,d), d fastest
  int d = idx & (DI_ - 1);
  int l = (idx >> 10) & (L_ - 1);
  int b = idx >> 20;
  int hh = l >> 5, ww = l & 31;
  float acc = cb[d];
  #pragma unroll
  for (int dh = -1; dh <= 1; ++dh) {
    int y = hh + dh;
    if ((unsigned)y >= 32u) continue;
    #pragma unroll
    for (int dw = -1; dw <= 1; ++dw) {
      int x = ww + dw;
      if ((unsigned)x >= 32u) continue;
      acc = fmaf(xz[((size_t)b * L_ + y * 32 + x) * (2 * DI_) + d],
                 cw[d * 9 + (dh + 1) * 3 + (dw + 1)], acc);
    }
  }
  float sv = acc / (1.f + __expf(-acc));
  xa[idx] = sv;
}

// ---------------- dt projection + softplus -> delta [b][k][l][d] ----------------
__global__ __launch_bounds__(256) void delta_kernel(
    const float* __restrict__ sp, const float* __restrict__ dtw,
    const float* __restrict__ dtb, float* __restrict__ delta) {
  int bk = blockIdx.x;
  int b = bk >> 2, k = bk & 3;
  int dc = blockIdx.y * 256;
  int l0 = blockIdx.z * 128;
  __shared__ float wl[32 * 257];
  __shared__ float rl[128 * 32];
  int tid = threadIdx.x;
  for (int i = tid; i < 256 * 32; i += 256) {
    int dl = i >> 5, r = i & 31;
    wl[r * 257 + dl] = dtw[((size_t)k * DI_ + dc + dl) * R_ + r];
  }
  for (int i = tid; i < 128 * 32; i += 256) {
    int ll = i >> 5, r = i & 31;
    rl[ll * 32 + r] = sp[((size_t)b * L_ + l0 + ll) * 384 + k * R_ + r];
  }
  __syncthreads();
  float bias = dtb[k * DI_ + dc + tid];
  for (int ll = 0; ll < 128; ++ll) {
    float acc = bias;
    #pragma unroll
    for (int r = 0; r < 32; ++r)
      acc = fmaf(rl[ll * 32 + r], wl[r * 257 + tid], acc);
    float dlt = (acc > 15.f) ? acc : log1pf(__expf(acc));
    delta[(((size_t)(b * 4 + k) * L_) + l0 + ll) * DI_ + dc + tid] = dlt;
  }
}

// ---------------- selective scan; writes y in-place over delta ----------------
__global__ __launch_bounds__(512) void scan_kernel(
    float* __restrict__ delta, const float* __restrict__ xa,
    const float* __restrict__ sp, const float* __restrict__ Cs,
    const float* __restrict__ A_logs, const float* __restrict__ Ds) {
  int dblk = blockIdx.x;  // 16 blocks of 64 d's
  int k = blockIdx.y, b = blockIdx.z;
  int tid = threadIdx.x, lane = tid & 63, wv = tid >> 6;
  int d = dblk * 64 + lane, n0 = wv * 8;
  int gd = k * DI_ + d;
  float a2[8], h[8];
  #pragma unroll
  for (int j = 0; j < 8; ++j) {
    a2[j] = -__expf(A_logs[(size_t)gd * N_ + n0 + j]) * 1.44269504f;
    h[j] = 0.f;
  }
  float dsv = Ds[gd];
  __shared__ float Bsh[16][64], Csh[16][64], DSh[16][64], Ush[16][64];
  __shared__ float yred[2][8][64];
  const size_t spB = (size_t)b * L_ * 384 + 128 + k * N_;
  const size_t csB = (size_t)b * L_ * 256 + k * N_;
  const size_t dlB = ((size_t)(b * 4 + k) * L_) * DI_ + dblk * 64;
  const size_t xaB = (size_t)b * L_ * DI_ + dblk * 64;
  for (int l0 = 0; l0 < L_; l0 += 16) {
    __syncthreads();
    for (int i = tid; i < 1024; i += 512) {
      int ll = i >> 6, nn = i & 63;
      int l = l0 + ll;
      Bsh[ll][nn] = sp[spB + (size_t)l * 384 + nn];
      Csh[ll][nn] = Cs[csB + (size_t)l * 256 + nn];
      DSh[ll][nn] = delta[dlB + (size_t)l * DI_ + nn];
      int lr = 1023 - l;
      int pos = (k == 0) ? l
              : (k == 1) ? ((l & 31) * 32 + (l >> 5))
              : (k == 2) ? lr
                         : ((lr & 31) * 32 + (lr >> 5));
      Ush[ll][nn] = xa[xaB + (size_t)pos * DI_ + nn];
    }
    __syncthreads();
    for (int li = 0; li < 16; ++li) {
      int l = l0 + li;
      float dlt = DSh[li][lane];
      float u = Ush[li][lane];
      float du = dlt * u;
      const float* bp = &Bsh[li][n0];
      const float* cp = &Csh[li][n0];
      float yp = 0.f;
      #pragma unroll
      for (int j = 0; j < 8; ++j) {
        float e = exp2f(dlt * a2[j]);
        h[j] = fmaf(e, h[j], du * bp[j]);
        yp = fmaf(h[j], cp[j], yp);
      }
      yred[l & 1][wv][lane] = yp;
      __syncthreads();
      if (wv == 0) {
        float s = 0.f;
        #pragma unroll
        for (int ww = 0; ww < 8; ++ww) s += yred[l & 1][ww][lane];
        s = fmaf(u, dsv, s);
        delta[dlB + (size_t)l * DI_ + lane] = s;  // overwrite consumed delta with y
      }
    }
  }
}

// ---------------- fuse: ygz = (sum_k yk) * z ----------------
__global__ __launch_bounds__(256) void fuse_ygz(
    const float* __restrict__ yk, const float* __restrict__ xz, float* __restrict__ ygz) {
  size_t i = (size_t)blockIdx.x * 256 + threadIdx.x;  // (b,l,d)
  size_t b = i >> 20, ld = i & ((1u << 20) - 1);
  float s = 0.f;
  #pragma unroll
  for (int k = 0; k < 4; ++k) s += yk[((size_t)(b * 4 + k) << 20) + ld];
  ygz[i] = s * xz[(i >> 10) * (2 * DI_) + DI_ + (i & (DI_ - 1))];
}

// ---------------- host ----------------
extern "C" void kernel_launch(void* const* d_in, const int* in_sizes, int n_in,
                              void* d_out, int out_size, void* d_ws, size_t ws_size,
                              hipStream_t stream) {
  (void)in_sizes; (void)n_in; (void)out_size; (void)ws_size;
  const float* content   = (const float*)d_in[0];
  const float* style     = (const float*)d_in[1];
  const float* norm1_w   = (const float*)d_in[2];
  const float* norm1_b   = (const float*)d_in[3];
  const float* in_proj_w = (const float*)d_in[4];
  const float* conv_w    = (const float*)d_in[5];
  const float* conv_b    = (const float*)d_in[6];
  const float* style_proj_w   = (const float*)d_in[7];
  const float* content_proj_w = (const float*)d_in[8];
  const float* dtw       = (const float*)d_in[9];
  const float* dtb       = (const float*)d_in[10];
  const float* A_logs    = (const float*)d_in[11];
  const float* Ds        = (const float*)d_in[12];
  const float* out_proj_w = (const float*)d_in[13];
  const float* norm2_w   = (const float*)d_in[14];
  const float* norm2_b   = (const float*)d_in[15];
  const float* mlp_w1    = (const float*)d_in[16];
  const float* mlp_b1    = (const float*)d_in[17];
  const float* mlp_w2    = (const float*)d_in[18];
  const float* mlp_b2    = (const float*)d_in[19];
  float* out = (float*)d_out;

  float* ws = (float*)d_ws;
  const size_t ROWS = (size_t)B_ * L_;  // 4096
  size_t o = 0;
  float* cn    = ws + o; o += ROWS * HID_;        // later reused as x1
  float* sn    = ws + o; o += ROWS * HID_;        // later reused as xn
  float* xz    = ws + o; o += ROWS * 2 * DI_;
  float* sp    = ws + o; o += ROWS * 384;
  float* xa    = ws + o; o += ROWS * DI_;
  float* csb   = ws + o; o += ROWS * 256;
  float* delta = ws + o; o += (size_t)B_ * K_ * L_ * DI_;  // later reused as mlp hidden
  float* ygz   = ws + o; o += ROWS * DI_;
  unsigned short* wt = (unsigned short*)(ws + o);
  unsigned short* inpT = wt;                    // (2048,512)
  unsigned short* styT = inpT + 2048 * 512;     // (384,512)
  unsigned short* conT = styT + 384 * 512;      // (256,1024)
  unsigned short* outT = conT + 256 * 1024;     // (512,1024)
  unsigned short* w1T  = outT + 512 * 1024;     // (2048,512)
  unsigned short* w2T  = w1T + 2048 * 512;      // (512,2048)
  float* x1 = cn;
  float* xn = sn;
  float* hmid = delta;  // 4096x2048 fits in delta's 16M floats

  // weight transpose+cast to bf16 (N,K)
  transpose_cast<<<dim3(2048 / 32, 512 / 32), 256, 0, stream>>>(in_proj_w, inpT, 512, 2048);
  transpose_cast<<<dim3(384 / 32, 512 / 32), 256, 0, stream>>>(style_proj_w, styT, 512, 384);
  transpose_cast<<<dim3(256 / 32, 1024 / 32), 256, 0, stream>>>(content_proj_w, conT, 1024, 256);
  transpose_cast<<<dim3(512 / 32, 1024 / 32), 256, 0, stream>>>(out_proj_w, outT, 1024, 512);
  transpose_cast<<<dim3(2048 / 32, 512 / 32), 256, 0, stream>>>(mlp_w1, w1T, 512, 2048);
  transpose_cast<<<dim3(512 / 32, 2048 / 32), 256, 0, stream>>>(mlp_w2, w2T, 2048, 512);

  // norm1 on content and style
  ln_kernel<<<ROWS / 4, 256, 0, stream>>>(content, cn, norm1_w, norm1_b);
  ln_kernel<<<ROWS / 4, 256, 0, stream>>>(style, sn, norm1_w, norm1_b);

  // xz = cn @ in_proj
  gemm_kernel<0><<<dim3(2048 / BN, ROWS / BM), 256, 0, stream>>>(
      cn, inpT, xz, ROWS, 2048, 512, nullptr, nullptr);
  // sp = sn @ style_proj
  gemm_kernel<0><<<dim3(384 / BN, ROWS / BM), 256, 0, stream>>>(
      sn, styT, sp, ROWS, 384, 512, nullptr, nullptr);
  // conv + silu -> xa
  conv_kernel<<<(ROWS * DI_) / 256, 256, 0, stream>>>(xz, conv_w, conv_b, xa);
  // Cs = xa @ content_proj
  gemm_kernel<0><<<dim3(256 / BN, ROWS / BM), 256, 0, stream>>>(
      xa, conT, csb, ROWS, 256, 1024, nullptr, nullptr);
  // delta = softplus(rank @ dtw + bias)
  delta_kernel<<<dim3(B_ * K_, DI_ / 256, L_ / 128), 256, 0, stream>>>(sp, dtw, dtb, delta);
  // selective scan (y overwrites delta)
  scan_kernel<<<dim3(DI_ / 64, K_, B_), 512, 0, stream>>>(delta, xa, sp, csb, A_logs, Ds);
  // ygz = (sum_k y) * z
  fuse_ygz<<<(ROWS * DI_) / 256, 256, 0, stream>>>(delta, xz, ygz);
  // x1 = content + ygz @ out_proj
  gemm_kernel<1><<<dim3(512 / BN, ROWS / BM), 256, 0, stream>>>(
      ygz, outT, x1, ROWS, 512, 1024, nullptr, content);
  // norm2
  ln_kernel<<<ROWS / 4, 256, 0, stream>>>(x1, xn, norm2_w, norm2_b);
  // mlp
  gemm_kernel<2><<<dim3(2048 / BN, ROWS / BM), 256, 0, stream>>>(
      xn, w1T, hmid, ROWS, 2048, 512, mlp_b1, nullptr);
  gemm_kernel<3><<<dim3(512 / BN, ROWS / BM), 256, 0, stream>>>(
      hmid, w2T, out, ROWS, 512, 2048, mlp_b2, x1);
}

// Round 2
// 679.668 us; speedup vs baseline: 1.3098x; 1.3098x over previous
//
#include <hip/hip_runtime.h>

// ---------------- constants ----------------
#define B_ 4
#define Hh_ 32
#define Ww_ 32
#define L_ 1024
#define HID_ 512
#define DI_ 1024
#define N_ 64
#define R_ 32
#define K_ 4
#define MLP_ 2048

typedef __bf16 bf16x8 __attribute__((ext_vector_type(8)));
typedef float f32x4 __attribute__((ext_vector_type(4)));

__device__ __forceinline__ unsigned short f2bf(float f) {
  unsigned int u = __builtin_bit_cast(unsigned int, f);
  return (unsigned short)((u + 0x7FFFu + ((u >> 16) & 1u)) >> 16);
}

// ---------------- transpose + cast weights: src (K,N) f32 -> dst (N,K) bf16 ----------------
__global__ __launch_bounds__(256) void transpose_cast(
    const float* __restrict__ src, unsigned short* __restrict__ dst, int K, int N) {
  __shared__ float t[32][33];
  int nb = blockIdx.x * 32, kb = blockIdx.y * 32;
  int tx = threadIdx.x & 31, ty = threadIdx.x >> 5;
  for (int r = ty; r < 32; r += 8) t[r][tx] = src[(size_t)(kb + r) * N + nb + tx];
  __syncthreads();
  for (int r = ty; r < 32; r += 8) dst[(size_t)(nb + r) * K + kb + tx] = f2bf(t[tx][r]);
}

// ---------------- LayerNorm over 512, wave per row ----------------
__global__ __launch_bounds__(256) void ln_kernel(
    const float* __restrict__ in, float* __restrict__ out,
    const float* __restrict__ w, const float* __restrict__ bb) {
  int row = blockIdx.x * 4 + (threadIdx.x >> 6);
  int lane = threadIdx.x & 63;
  const float* p = in + (size_t)row * HID_;
  float4 v0 = *(const float4*)(p + lane * 4);
  float4 v1 = *(const float4*)(p + 256 + lane * 4);
  float s = v0.x + v0.y + v0.z + v0.w + v1.x + v1.y + v1.z + v1.w;
  float q = v0.x * v0.x + v0.y * v0.y + v0.z * v0.z + v0.w * v0.w +
            v1.x * v1.x + v1.y * v1.y + v1.z * v1.z + v1.w * v1.w;
  #pragma unroll
  for (int m = 1; m < 64; m <<= 1) { s += __shfl_xor(s, m, 64); q += __shfl_xor(q, m, 64); }
  float mean = s * (1.f / 512.f);
  float var = q * (1.f / 512.f) - mean * mean;
  float rstd = rsqrtf(var + 1e-5f);
  float4 w0 = *(const float4*)(w + lane * 4);
  float4 w1 = *(const float4*)(w + 256 + lane * 4);
  float4 b0 = *(const float4*)(bb + lane * 4);
  float4 b1 = *(const float4*)(bb + 256 + lane * 4);
  float* o = out + (size_t)row * HID_;
  float4 r0, r1;
  r0.x = (v0.x - mean) * rstd * w0.x + b0.x;
  r0.y = (v0.y - mean) * rstd * w0.y + b0.y;
  r0.z = (v0.z - mean) * rstd * w0.z + b0.z;
  r0.w = (v0.w - mean) * rstd * w0.w + b0.w;
  r1.x = (v1.x - mean) * rstd * w1.x + b1.x;
  r1.y = (v1.y - mean) * rstd * w1.y + b1.y;
  r1.z = (v1.z - mean) * rstd * w1.z + b1.z;
  r1.w = (v1.w - mean) * rstd * w1.w + b1.w;
  *(float4*)(o + lane * 4) = r0;
  *(float4*)(o + 256 + lane * 4) = r1;
}

// ---------------- MFMA GEMM: A (M,K) f32, BT (N,K) bf16, C (M,N) f32 ----------------
// EPI: 0 = plain, 1 = +resid, 2 = +bias then exact gelu, 3 = +bias +resid
#define BM 128
#define BN 128
#define BK 32
#define LST 40  // LDS row stride in bf16 units (80B, 16B-aligned, conflict-light)

template <int EPI>
__global__ __launch_bounds__(256) void gemm_kernel(
    const float* __restrict__ A, const unsigned short* __restrict__ BT,
    float* __restrict__ C, int M, int N, int K,
    const float* __restrict__ bias, const float* __restrict__ resid) {
  __shared__ __align__(16) unsigned short As[BM * LST];
  __shared__ __align__(16) unsigned short Bs[BN * LST];
  int tid = threadIdx.x;
  int lane = tid & 63, wv = tid >> 6;
  int wm = wv >> 1, wn = wv & 1;
  int m0 = blockIdx.y * BM, n0 = blockIdx.x * BN;
  f32x4 acc[4][4] = {};
  int sr = tid >> 3, sc = (tid & 7) * 4;
  int kk = (lane >> 4) * 8;
  int rA = wm * 64 + (lane & 15);
  int rB = wn * 64 + (lane & 15);
  for (int k0 = 0; k0 < K; k0 += BK) {
    __syncthreads();
    #pragma unroll
    for (int p = 0; p < 4; ++p) {
      int r = sr + p * 32;
      float4 av = *(const float4*)(A + (size_t)(m0 + r) * K + k0 + sc);
      unsigned int lo = (unsigned int)f2bf(av.x) | ((unsigned int)f2bf(av.y) << 16);
      unsigned int hi = (unsigned int)f2bf(av.z) | ((unsigned int)f2bf(av.w) << 16);
      *(uint2*)&As[r * LST + sc] = make_uint2(lo, hi);
      uint2 bv = *(const uint2*)(BT + (size_t)(n0 + r) * K + k0 + sc);
      *(uint2*)&Bs[r * LST + sc] = bv;
    }
    __syncthreads();
    bf16x8 fa[4], fb[4];
    #pragma unroll
    for (int i = 0; i < 4; ++i) {
      fa[i] = *(const bf16x8*)&As[(rA + i * 16) * LST + kk];
      fb[i] = *(const bf16x8*)&Bs[(rB + i * 16) * LST + kk];
    }
    #pragma unroll
    for (int i = 0; i < 4; ++i)
      #pragma unroll
      for (int j = 0; j < 4; ++j)
        acc[i][j] = __builtin_amdgcn_mfma_f32_16x16x32_bf16(fa[i], fb[j], acc[i][j], 0, 0, 0);
  }
  int crow0 = m0 + wm * 64 + (lane >> 4) * 4, ccol0 = n0 + wn * 64 + (lane & 15);
  #pragma unroll
  for (int i = 0; i < 4; ++i) {
    #pragma unroll
    for (int j = 0; j < 4; ++j) {
      int col = ccol0 + j * 16;
      #pragma unroll
      for (int r = 0; r < 4; ++r) {
        int row = crow0 + i * 16 + r;
        float v = acc[i][j][r];
        if (EPI == 1) v += resid[(size_t)row * N + col];
        if (EPI == 2) { v += bias[col]; v = 0.5f * v * (1.f + erff(v * 0.70710678f)); }
        if (EPI == 3) v += bias[col] + resid[(size_t)row * N + col];
        C[(size_t)row * N + col] = v;
      }
    }
  }
}

// ---------------- depthwise 3x3 conv + bias + SiLU (channels-last) ----------------
__global__ __launch_bounds__(256) void conv_kernel(
    const float* __restrict__ xz, const float* __restrict__ cw,
    const float* __restrict__ cb, float* __restrict__ xa) {
  int idx = blockIdx.x * 256 + threadIdx.x;  // (b,l,d), d fastest
  int d = idx & (DI_ - 1);
  int l = (idx >> 10) & (L_ - 1);
  int b = idx >> 20;
  int hh = l >> 5, ww = l & 31;
  float acc = cb[d];
  #pragma unroll
  for (int dh = -1; dh <= 1; ++dh) {
    int y = hh + dh;
    if ((unsigned)y >= 32u) continue;
    #pragma unroll
    for (int dw = -1; dw <= 1; ++dw) {
      int x = ww + dw;
      if ((unsigned)x >= 32u) continue;
      acc = fmaf(xz[((size_t)b * L_ + y * 32 + x) * (2 * DI_) + d],
                 cw[d * 9 + (dh + 1) * 3 + (dw + 1)], acc);
    }
  }
  float sv = acc / (1.f + __expf(-acc));
  xa[idx] = sv;
}

// ---------------- dt projection + softplus -> delta [b][k][l][d] ----------------
__global__ __launch_bounds__(256) void delta_kernel(
    const float* __restrict__ sp, const float* __restrict__ dtw,
    const float* __restrict__ dtb, float* __restrict__ delta) {
  int bk = blockIdx.x;
  int b = bk >> 2, k = bk & 3;
  int dc = blockIdx.y * 256;
  int l0 = blockIdx.z * 128;
  __shared__ float wl[32 * 257];
  __shared__ float rl[128 * 32];
  int tid = threadIdx.x;
  for (int i = tid; i < 256 * 32; i += 256) {
    int dl = i >> 5, r = i & 31;
    wl[r * 257 + dl] = dtw[((size_t)k * DI_ + dc + dl) * R_ + r];
  }
  for (int i = tid; i < 128 * 32; i += 256) {
    int ll = i >> 5, r = i & 31;
    rl[ll * 32 + r] = sp[((size_t)b * L_ + l0 + ll) * 384 + k * R_ + r];
  }
  __syncthreads();
  float bias = dtb[k * DI_ + dc + tid];
  for (int ll = 0; ll < 128; ++ll) {
    float acc = bias;
    #pragma unroll
    for (int r = 0; r < 32; ++r)
      acc = fmaf(rl[ll * 32 + r], wl[r * 257 + tid], acc);
    float dlt = (acc > 15.f) ? acc : log1pf(__expf(acc));
    delta[(((size_t)(b * 4 + k) * L_) + l0 + ll) * DI_ + dc + tid] = dlt;
  }
}

// ---------------- selective scan; writes y in-place over delta ----------------
// Wave layout: lane = ng*8 + dg. Each lane owns (1 d, 8 n); wave owns 8 d x 64 n.
// n-reduction is 3 intra-wave shfl_xor; NO syncthreads in the time loop.
#define CH 16
__global__ __launch_bounds__(512) void scan_kernel(
    float* __restrict__ delta, const float* __restrict__ xa,
    const float* __restrict__ sp, const float* __restrict__ Cs,
    const float* __restrict__ A_logs, const float* __restrict__ Ds) {
  int dblk = blockIdx.x;  // 16 blocks of 64 d's
  int k = blockIdx.y, b = blockIdx.z;
  int tid = threadIdx.x, lane = tid & 63, wv = tid >> 6;
  int dg = lane & 7, ng = lane >> 3;
  int wd = wv * 8 + dg;              // d within block's 64
  int gd = k * DI_ + dblk * 64 + wd;
  float a2[8], h[8];
  #pragma unroll
  for (int j = 0; j < 8; ++j) {
    a2[j] = -__expf(A_logs[(size_t)gd * N_ + ng * 8 + j]) * 1.44269504f;
    h[j] = 0.f;
  }
  float dsv = Ds[gd];
  __shared__ float Bsh[2][CH][64], Csh[2][CH][64], DSh[2][CH][64], Ush[2][CH][64];
  __shared__ float yl[CH][64];
  const size_t spB = (size_t)b * L_ * 384 + 128 + k * N_;
  const size_t csB = (size_t)b * L_ * 256 + k * N_;
  const size_t dlB = ((size_t)(b * 4 + k) * L_) * DI_ + dblk * 64;
  const size_t xaB = (size_t)b * L_ * DI_ + dblk * 64;
  // staging role: waves 0-3 load B/C, waves 4-7 load D/U (wave-uniform branch)
  int sa = tid >> 8;
  int sr = tid & 255;
  int sll = sr >> 4, sn4 = (sr & 15) * 4;
  auto posf = [&](int l) {
    int lr = 1023 - l;
    return (k == 0) ? l
         : (k == 1) ? ((l & 31) * 32 + (l >> 5))
         : (k == 2) ? lr
                    : ((lr & 31) * 32 + (lr >> 5));
  };
  // stage chunk 0
  {
    int l = sll;
    if (sa == 0) {
      *(float4*)&Bsh[0][sll][sn4] = *(const float4*)(sp + spB + (size_t)l * 384 + sn4);
      *(float4*)&Csh[0][sll][sn4] = *(const float4*)(Cs + csB + (size_t)l * 256 + sn4);
    } else {
      *(float4*)&DSh[0][sll][sn4] = *(const float4*)(delta + dlB + (size_t)l * DI_ + sn4);
      *(float4*)&Ush[0][sll][sn4] = *(const float4*)(xa + xaB + (size_t)posf(l) * DI_ + sn4);
    }
  }
  __syncthreads();
  for (int c = 0; c < L_ / CH; ++c) {
    int bb = c & 1;
    float4 r0, r1;
    if (c < L_ / CH - 1) {  // prefetch next chunk into registers
      int l = (c + 1) * CH + sll;
      if (sa == 0) {
        r0 = *(const float4*)(sp + spB + (size_t)l * 384 + sn4);
        r1 = *(const float4*)(Cs + csB + (size_t)l * 256 + sn4);
      } else {
        r0 = *(const float4*)(delta + dlB + (size_t)l * DI_ + sn4);
        r1 = *(const float4*)(xa + xaB + (size_t)posf(l) * DI_ + sn4);
      }
    }
    #pragma unroll
    for (int li = 0; li < CH; ++li) {
      float dlt = DSh[bb][li][wd];
      float u = Ush[bb][li][wd];
      float du = dlt * u;
      float4 b0 = *(const float4*)&Bsh[bb][li][ng * 8];
      float4 b1 = *(const float4*)&Bsh[bb][li][ng * 8 + 4];
      float4 c0 = *(const float4*)&Csh[bb][li][ng * 8];
      float4 c1 = *(const float4*)&Csh[bb][li][ng * 8 + 4];
      float bv[8] = {b0.x, b0.y, b0.z, b0.w, b1.x, b1.y, b1.z, b1.w};
      float cv[8] = {c0.x, c0.y, c0.z, c0.w, c1.x, c1.y, c1.z, c1.w};
      float yp = 0.f;
      #pragma unroll
      for (int j = 0; j < 8; ++j) {
        float e = __builtin_amdgcn_exp2f(dlt * a2[j]);
        h[j] = fmaf(e, h[j], du * bv[j]);
        yp = fmaf(h[j], cv[j], yp);
      }
      yp += __shfl_xor(yp, 8, 64);
      yp += __shfl_xor(yp, 16, 64);
      yp += __shfl_xor(yp, 32, 64);
      if (ng == 0) yl[li][wd] = fmaf(u, dsv, yp);
    }
    __syncthreads();  // compute done: yl complete, LDS buf bb free of readers
    if (c < L_ / CH - 1) {
      if (sa == 0) {
        *(float4*)&Bsh[bb ^ 1][sll][sn4] = r0;
        *(float4*)&Csh[bb ^ 1][sll][sn4] = r1;
      } else {
        *(float4*)&DSh[bb ^ 1][sll][sn4] = r0;
        *(float4*)&Ush[bb ^ 1][sll][sn4] = r1;
      }
    }
    if (tid < 256) {  // coalesced y writeback (overwrites consumed delta rows)
      int ll = tid >> 4, n4 = (tid & 15) * 4;
      *(float4*)(delta + dlB + (size_t)(c * CH + ll) * DI_ + n4) = *(const float4*)&yl[ll][n4];
    }
    __syncthreads();  // staging visible; yl free to overwrite in chunk c+1
  }
}

// ---------------- fuse: ygz = (sum_k yk) * z ----------------
__global__ __launch_bounds__(256) void fuse_ygz(
    const float* __restrict__ yk, const float* __restrict__ xz, float* __restrict__ ygz) {
  size_t i = (size_t)blockIdx.x * 256 + threadIdx.x;  // (b,l,d)
  size_t b = i >> 20, ld = i & ((1u << 20) - 1);
  float s = 0.f;
  #pragma unroll
  for (int k = 0; k < 4; ++k) s += yk[((size_t)(b * 4 + k) << 20) + ld];
  ygz[i] = s * xz[(i >> 10) * (2 * DI_) + DI_ + (i & (DI_ - 1))];
}

// ---------------- host ----------------
extern "C" void kernel_launch(void* const* d_in, const int* in_sizes, int n_in,
                              void* d_out, int out_size, void* d_ws, size_t ws_size,
                              hipStream_t stream) {
  (void)in_sizes; (void)n_in; (void)out_size; (void)ws_size;
  const float* content   = (const float*)d_in[0];
  const float* style     = (const float*)d_in[1];
  const float* norm1_w   = (const float*)d_in[2];
  const float* norm1_b   = (const float*)d_in[3];
  const float* in_proj_w = (const float*)d_in[4];
  const float* conv_w    = (const float*)d_in[5];
  const float* conv_b    = (const float*)d_in[6];
  const float* style_proj_w   = (const float*)d_in[7];
  const float* content_proj_w = (const float*)d_in[8];
  const float* dtw       = (const float*)d_in[9];
  const float* dtb       = (const float*)d_in[10];
  const float* A_logs    = (const float*)d_in[11];
  const float* Ds        = (const float*)d_in[12];
  const float* out_proj_w = (const float*)d_in[13];
  const float* norm2_w   = (const float*)d_in[14];
  const float* norm2_b   = (const float*)d_in[15];
  const float* mlp_w1    = (const float*)d_in[16];
  const float* mlp_b1    = (const float*)d_in[17];
  const float* mlp_w2    = (const float*)d_in[18];
  const float* mlp_b2    = (const float*)d_in[19];
  float* out = (float*)d_out;

  float* ws = (float*)d_ws;
  const size_t ROWS = (size_t)B_ * L_;  // 4096
  size_t o = 0;
  float* cn    = ws + o; o += ROWS * HID_;        // later reused as x1
  float* sn    = ws + o; o += ROWS * HID_;        // later reused as xn
  float* xz    = ws + o; o += ROWS * 2 * DI_;
  float* sp    = ws + o; o += ROWS * 384;
  float* xa    = ws + o; o += ROWS * DI_;
  float* csb   = ws + o; o += ROWS * 256;
  float* delta = ws + o; o += (size_t)B_ * K_ * L_ * DI_;  // later reused as mlp hidden
  float* ygz   = ws + o; o += ROWS * DI_;
  unsigned short* wt = (unsigned short*)(ws + o);
  unsigned short* inpT = wt;                    // (2048,512)
  unsigned short* styT = inpT + 2048 * 512;     // (384,512)
  unsigned short* conT = styT + 384 * 512;      // (256,1024)
  unsigned short* outT = conT + 256 * 1024;     // (512,1024)
  unsigned short* w1T  = outT + 512 * 1024;     // (2048,512)
  unsigned short* w2T  = w1T + 2048 * 512;      // (512,2048)
  float* x1 = cn;
  float* xn = sn;
  float* hmid = delta;  // 4096x2048 fits in delta's 16M floats

  // weight transpose+cast to bf16 (N,K)
  transpose_cast<<<dim3(2048 / 32, 512 / 32), 256, 0, stream>>>(in_proj_w, inpT, 512, 2048);
  transpose_cast<<<dim3(384 / 32, 512 / 32), 256, 0, stream>>>(style_proj_w, styT, 512, 384);
  transpose_cast<<<dim3(256 / 32, 1024 / 32), 256, 0, stream>>>(content_proj_w, conT, 1024, 256);
  transpose_cast<<<dim3(512 / 32, 1024 / 32), 256, 0, stream>>>(out_proj_w, outT, 1024, 512);
  transpose_cast<<<dim3(2048 / 32, 512 / 32), 256, 0, stream>>>(mlp_w1, w1T, 512, 2048);
  transpose_cast<<<dim3(512 / 32, 2048 / 32), 256, 0, stream>>>(mlp_w2, w2T, 2048, 512);

  // norm1 on content and style
  ln_kernel<<<ROWS / 4, 256, 0, stream>>>(content, cn, norm1_w, norm1_b);
  ln_kernel<<<ROWS / 4, 256, 0, stream>>>(style, sn, norm1_w, norm1_b);

  // xz = cn @ in_proj
  gemm_kernel<0><<<dim3(2048 / BN, ROWS / BM), 256, 0, stream>>>(
      cn, inpT, xz, ROWS, 2048, 512, nullptr, nullptr);
  // sp = sn @ style_proj
  gemm_kernel<0><<<dim3(384 / BN, ROWS / BM), 256, 0, stream>>>(
      sn, styT, sp, ROWS, 384, 512, nullptr, nullptr);
  // conv + silu -> xa
  conv_kernel<<<(ROWS * DI_) / 256, 256, 0, stream>>>(xz, conv_w, conv_b, xa);
  // Cs = xa @ content_proj
  gemm_kernel<0><<<dim3(256 / BN, ROWS / BM), 256, 0, stream>>>(
      xa, conT, csb, ROWS, 256, 1024, nullptr, nullptr);
  // delta = softplus(rank @ dtw + bias)
  delta_kernel<<<dim3(B_ * K_, DI_ / 256, L_ / 128), 256, 0, stream>>>(sp, dtw, dtb, delta);
  // selective scan (y overwrites delta)
  scan_kernel<<<dim3(DI_ / 64, K_, B_), 512, 0, stream>>>(delta, xa, sp, csb, A_logs, Ds);
  // ygz = (sum_k y) * z
  fuse_ygz<<<(ROWS * DI_) / 256, 256, 0, stream>>>(delta, xz, ygz);
  // x1 = content + ygz @ out_proj
  gemm_kernel<1><<<dim3(512 / BN, ROWS / BM), 256, 0, stream>>>(
      ygz, outT, x1, ROWS, 512, 1024, nullptr, content);
  // norm2
  ln_kernel<<<ROWS / 4, 256, 0, stream>>>(x1, xn, norm2_w, norm2_b);
  // mlp
  gemm_kernel<2><<<dim3(2048 / BN, ROWS / BM), 256, 0, stream>>>(
      xn, w1T, hmid, ROWS, 2048, 512, mlp_b1, nullptr);
  gemm_kernel<3><<<dim3(512 / BN, ROWS / BM), 256, 0, stream>>>(
      hmid, w2T, out, ROWS, 512, 2048, mlp_b2, x1);
}